// Round 1
// baseline (149.060 us; speedup 1.0000x reference)
//
#include <hip/hip_runtime.h>
#include <math.h>

#define DEP   96
#define HEADS 96
#define BSZ   16
#define DIM   512
#define REL   128
#define RELP  129   // REL + nil

typedef __attribute__((ext_vector_type(8))) _Float16  half8;    // 8 fp16 (4 VGPRs)
typedef __attribute__((ext_vector_type(2))) __fp16    fp16x2;   // cvt_pkrtz return type
typedef __attribute__((ext_vector_type(4))) float     floatx4;

__device__ __forceinline__ unsigned short f2h(float x) {
    union { _Float16 h; unsigned short u; } c;
    c.h = (_Float16)x;                                   // v_cvt_f16_f32 (RNE)
    return c.u;
}
// two f32 -> packed 2xf16 in one v_cvt_pkrtz_f16_f32
__device__ __forceinline__ unsigned pk_f2h(float a, float b) {
    union { fp16x2 h; unsigned u; } c;
    c.h = __builtin_amdgcn_cvt_pkrtz(a, b);
    return c.u;
}
// packed fp16 add / relu (VOP3P)
__device__ __forceinline__ unsigned pk_add_h2(unsigned a, unsigned b) {
    unsigned r; asm("v_pk_add_f16 %0, %1, %2" : "=v"(r) : "v"(a), "v"(b)); return r;
}
__device__ __forceinline__ unsigned pk_max_h2(unsigned a, unsigned b) {
    unsigned r; asm("v_pk_max_f16 %0, %1, %2" : "=v"(r) : "v"(a), "v"(b)); return r;
}

#define PSS 72   // LDS row stride (fp16 elems): 144 B = 16B-aligned, ~2-way banks (free)

// ---------------------------------------------------------------------------
// Kernel A: projections via fp16 MFMA. Wt cast inline (cvt_kernel removed);
// first 32 blocks additionally cast Wp -> WpH as a prelude (8192 x uint4).
//   z=0: P1[m][n] = outs@Wt[:, :512]^T + bt   (f32 out)
//   z=1: P2H[m][n]= graph@Wt[:, 512:]^T       (fp16 out)
// 64x64 tile, BK=64, 256 threads = 4 waves; wave w owns m-rows [16w,16w+16).
// ---------------------------------------------------------------------------
__global__ __launch_bounds__(256) void proj_kernel(
    const float* __restrict__ outs, const float* __restrict__ graph,
    const float* __restrict__ Wt, const float* __restrict__ bt,
    const float* __restrict__ Wp,
    float* __restrict__ P1, unsigned short* __restrict__ P2H,
    unsigned short* __restrict__ WpH)
{
    // ---- Wp f32 -> fp16 prelude (replaces cvt_kernel): 32 blocks x 256 thr ----
    {
        const int fb = (blockIdx.z * gridDim.y + blockIdx.y) * gridDim.x + blockIdx.x;
        if (fb < 32) {
            const int c = fb * 256 + (int)threadIdx.x;       // 0..8191 chunks of 8
            float4 a = *(const float4*)(Wp + (size_t)c * 8);
            float4 b = *(const float4*)(Wp + (size_t)c * 8 + 4);
            uint4 o;
            o.x = pk_f2h(a.x, a.y); o.y = pk_f2h(a.z, a.w);
            o.z = pk_f2h(b.x, b.y); o.w = pk_f2h(b.z, b.w);
            *(uint4*)(WpH + (size_t)c * 8) = o;
        }
    }

    const int z = blockIdx.z;
    const float* A = z ? graph : outs;
    const int off  = z ? DIM : 0;
    const int row0 = blockIdx.y * 64;
    const int col0 = blockIdx.x * 64;

    __shared__ __align__(16) unsigned short As[64 * PSS];   // [m][k] fp16
    __shared__ __align__(16) unsigned short Ws[64 * PSS];   // [n][k] fp16

    const int tid  = threadIdx.x;
    const int lane = tid & 63;
    const int wv   = tid >> 6;          // 0..3
    const int ln15 = lane & 15;
    const int quad = lane >> 4;

    floatx4 acc[4];
    #pragma unroll
    for (int nt = 0; nt < 4; ++nt) acc[nt] = (floatx4){0.f,0.f,0.f,0.f};

    for (int kt = 0; kt < DIM; kt += 64) {
        // A: f32 load + packed RTZ cast to fp16 LDS (8 elems/slot, 2 slots)
        #pragma unroll
        for (int q = 0; q < 2; ++q) {
            const int slot = q*256 + tid;       // 0..511
            const int r  = slot >> 3;           // 0..63
            const int e8 = (slot & 7) * 8;
            const float* p = A + (size_t)(row0 + r) * DIM + kt + e8;
            float4 va = *(const float4*)p;
            float4 vb = *(const float4*)(p + 4);
            uint4 o;
            o.x = pk_f2h(va.x, va.y); o.y = pk_f2h(va.z, va.w);
            o.z = pk_f2h(vb.x, vb.y); o.w = pk_f2h(vb.z, vb.w);
            *(uint4*)&As[r * PSS + e8] = o;
        }
        // Wt: f32 load + cast (was pre-cast fp16 copy; cvt launch eliminated)
        #pragma unroll
        for (int q = 0; q < 2; ++q) {
            const int slot = q*256 + tid;       // 0..511
            const int r  = slot >> 3;           // 0..63
            const int e8 = (slot & 7) * 8;
            const float* p = Wt + (size_t)(col0 + r) * (2*DIM) + off + kt + e8;
            float4 va = *(const float4*)p;
            float4 vb = *(const float4*)(p + 4);
            uint4 o;
            o.x = pk_f2h(va.x, va.y); o.y = pk_f2h(va.z, va.w);
            o.z = pk_f2h(vb.x, vb.y); o.w = pk_f2h(vb.z, vb.w);
            *(uint4*)&Ws[r * PSS + e8] = o;
        }
        __syncthreads();
        #pragma unroll
        for (int ks = 0; ks < 64; ks += 32) {
            half8 af = *(const half8*)&As[(wv*16 + ln15) * PSS + ks + quad*8];
            #pragma unroll
            for (int nt = 0; nt < 4; ++nt) {
                half8 bf8 = *(const half8*)&Ws[(nt*16 + ln15) * PSS + ks + quad*8];
                acc[nt] = __builtin_amdgcn_mfma_f32_16x16x32_f16(af, bf8, acc[nt], 0, 0, 0);
            }
        }
        __syncthreads();
    }

    #pragma unroll
    for (int nt = 0; nt < 4; ++nt) {
        #pragma unroll
        for (int reg = 0; reg < 4; ++reg) {
            const int m = row0 + wv*16 + quad*4 + reg;
            const int n = col0 + nt*16 + ln15;
            float v = acc[nt][reg];
            if (!z) P1[(size_t)m * DIM + n] = v + bt[n];
            else    P2H[(size_t)m * DIM + n] = f2h(v);
        }
    }
}

// ---------------------------------------------------------------------------
// Kernel B: fused pairwise relu + fp16-MFMA GEMM + log_softmax(129).
// NEW: each block handles TWO dep rows (d0, d0+1) at the same b.
//   - ws (Wp tile) staged once, B-fragments read once -> reused for both db's
//   - P2H tile loaded once from L2, fed through two different drow addends
//   - per-db LDS b128 wave-ops drop 84 -> 64 (theory: fused is LDS-bound)
// Per-thread drow addend is ONE uint4/db/kt since (q*256+tid)&7 == tid&7.
// 256 threads = 4 waves; wave (mh,nh) owns the 48m x 64n quadrant of each db.
// LDS 50 KB -> 3 blocks/CU; launch_bounds(256,3) caps VGPR at 168 (acc=96).
// ---------------------------------------------------------------------------
#define HSS 72
#define WSS 72

__global__ __launch_bounds__(256, 3) void fused_kernel(
    const float* __restrict__ P1, const unsigned short* __restrict__ P2H,
    const unsigned short* __restrict__ WpH, const float* __restrict__ bp,
    float* __restrict__ out)
{
    const int bid = blockIdx.x;         // 0..767
    const int b   = bid & 15;
    const int db0 = ((bid >> 4) * 2) * 16 + b;      // pair: db0, db0+16

    __shared__ __align__(16) unsigned short drowH[2][DIM];   // dep rows fp16
    __shared__ __align__(16) unsigned short hs[2][96 * HSS]; // h tiles [m][k]
    __shared__ __align__(16) unsigned short ws[128 * WSS];   // Wp tile [n][k]
    __shared__ float pmx[2][96][2];     // softmax partials per (db, row, col-half)
    __shared__ float pl [2][96][2];

    const int tid  = threadIdx.x;       // 0..255
    const int lane = tid & 63;
    const int wv   = tid >> 6;          // 0..3
    const int ln15 = lane & 15;
    const int quad = lane >> 4;
    const int mh   = wv & 1;            // row half: [48*mh, 48*mh+48)
    const int nh   = wv >> 1;           // col half: [64*nh, 64*nh+64)
    const int e8   = (tid & 7) * 8;     // k-slot, constant across staging q's
    const int hb   = tid >> 3;          // 0..31

    // dep rows f32 -> fp16 (one-time)
    #pragma unroll
    for (int g = 0; g < 2; ++g) {
        float2 v = *(const float2*)(P1 + (size_t)(db0 + g*16) * DIM + tid*2);
        *(unsigned*)&drowH[g][tid*2] = pk_f2h(v.x, v.y);
    }
    __syncthreads();

    floatx4 acc[2][3][4];
    #pragma unroll
    for (int g = 0; g < 2; ++g)
        #pragma unroll
        for (int i = 0; i < 3; ++i)
            #pragma unroll
            for (int j = 0; j < 4; ++j) acc[g][i][j] = (floatx4){0.f,0.f,0.f,0.f};

    for (int kt = 0; kt < DIM; kt += 64) {
        // per-thread drow addends for this k-tile (single b128 read each)
        uint4 dv0 = *(const uint4*)&drowH[0][kt + e8];
        uint4 dv1 = *(const uint4*)&drowH[1][kt + e8];
        // ---- stage hs[g][h][e] = fp16 relu(drow_g[e] + P2H[h,b,e]), 2x 96x64 ----
        #pragma unroll
        for (int q = 0; q < 3; ++q) {
            const int h = q*32 + hb;             // 0..95
            uint4 pv = *(const uint4*)(P2H + ((size_t)h * BSZ + b) * DIM + kt + e8);
            uint4 o0, o1;
            o0.x = pk_max_h2(pk_add_h2(pv.x, dv0.x), 0u);
            o0.y = pk_max_h2(pk_add_h2(pv.y, dv0.y), 0u);
            o0.z = pk_max_h2(pk_add_h2(pv.z, dv0.z), 0u);
            o0.w = pk_max_h2(pk_add_h2(pv.w, dv0.w), 0u);
            o1.x = pk_max_h2(pk_add_h2(pv.x, dv1.x), 0u);
            o1.y = pk_max_h2(pk_add_h2(pv.y, dv1.y), 0u);
            o1.z = pk_max_h2(pk_add_h2(pv.z, dv1.z), 0u);
            o1.w = pk_max_h2(pk_add_h2(pv.w, dv1.w), 0u);
            *(uint4*)&hs[0][h * HSS + e8] = o0;
            *(uint4*)&hs[1][h * HSS + e8] = o1;
        }
        // ---- stage ws[r][e] = WpH[r][kt+e], 128x64 (shared by both db's) ----
        #pragma unroll
        for (int q = 0; q < 4; ++q) {
            const int r = q*32 + hb;             // 0..127
            *(uint4*)&ws[r * WSS + e8] =
                *(const uint4*)(WpH + (size_t)r * DIM + kt + e8);
        }
        __syncthreads();

        #pragma unroll
        for (int ks = 0; ks < 64; ks += 32) {
            half8 bf[4];
            #pragma unroll
            for (int nt = 0; nt < 4; ++nt)
                bf[nt] = *(const half8*)&ws[(nh*64 + nt*16 + ln15) * WSS + ks + quad*8];
            #pragma unroll
            for (int g = 0; g < 2; ++g) {
                #pragma unroll
                for (int mt = 0; mt < 3; ++mt) {
                    half8 af = *(const half8*)&hs[g][(mh*48 + mt*16 + ln15) * HSS + ks + quad*8];
                    #pragma unroll
                    for (int nt = 0; nt < 4; ++nt)
                        acc[g][mt][nt] = __builtin_amdgcn_mfma_f32_16x16x32_f16(
                            af, bf[nt], acc[g][mt][nt], 0, 0, 0);
                }
            }
        }
        __syncthreads();
    }

    // ---- epilogue phase 1: per-quadrant softmax partials (no nil yet) ----
    float bpv[4];
    #pragma unroll
    for (int nt = 0; nt < 4; ++nt) bpv[nt] = bp[nh*64 + nt*16 + ln15];

    #pragma unroll
    for (int g = 0; g < 2; ++g) {
        #pragma unroll
        for (int mt = 0; mt < 3; ++mt) {
            #pragma unroll
            for (int reg = 0; reg < 4; ++reg) {
                const int m = mh*48 + mt*16 + quad*4 + reg;
                float s[4];
                float mx = -1e30f;
                #pragma unroll
                for (int nt = 0; nt < 4; ++nt) {
                    s[nt] = acc[g][mt][nt][reg] + bpv[nt];
                    mx = fmaxf(mx, s[nt]);
                }
                #pragma unroll
                for (int msk = 1; msk < 16; msk <<= 1) mx = fmaxf(mx, __shfl_xor(mx, msk));
                float l = 0.f;
                #pragma unroll
                for (int nt = 0; nt < 4; ++nt) l += __expf(s[nt] - mx);
                #pragma unroll
                for (int msk = 1; msk < 16; msk <<= 1) l += __shfl_xor(l, msk);
                if (ln15 == 0) { pmx[g][m][nh] = mx; pl[g][m][nh] = l; }
            }
        }
    }
    __syncthreads();

    // ---- epilogue phase 2: combine halves + nil, write out ----
    #pragma unroll
    for (int g = 0; g < 2; ++g) {
        const size_t dbg = (size_t)(db0 + g*16);
        #pragma unroll
        for (int mt = 0; mt < 3; ++mt) {
            #pragma unroll
            for (int reg = 0; reg < 4; ++reg) {
                const int m = mh*48 + mt*16 + quad*4 + reg;
                const float mx0 = pmx[g][m][0], mx1 = pmx[g][m][1];
                const float l0  = pl[g][m][0],  l1  = pl[g][m][1];
                const float MX = fmaxf(fmaxf(mx0, mx1), 0.f);   // nil = 0 in max
                const float L  = l0 * __expf(mx0 - MX) + l1 * __expf(mx1 - MX)
                               + __expf(-MX);                    // nil term
                const float lse = MX + __logf(L);

                const size_t base = (dbg * HEADS + m) * RELP;
                #pragma unroll
                for (int nt = 0; nt < 4; ++nt)
                    out[base + 1 + nh*64 + nt*16 + ln15] = acc[g][mt][nt][reg] + bpv[nt] - lse;
                if (nh == 0 && ln15 == 0) out[base] = -lse;
            }
        }
    }
}

extern "C" void kernel_launch(void* const* d_in, const int* in_sizes, int n_in,
                              void* d_out, int out_size, void* d_ws, size_t ws_size,
                              hipStream_t stream) {
    const float* outs  = (const float*)d_in[0];
    const float* graph = (const float*)d_in[1];
    const float* Wt    = (const float*)d_in[2];
    const float* bt    = (const float*)d_in[3];
    const float* Wp    = (const float*)d_in[4];
    const float* bp    = (const float*)d_in[5];
    float* out = (float*)d_out;

    // Workspace: 4,849,664 B (WtH eliminated; Wt cast inline in proj).
    float* P1           = (float*)d_ws;                     // [1536][512] f32   (3 MB)
    unsigned short* P2H = (unsigned short*)(P1 + 786432);   // [1536][512] fp16  (1.5 MB)
    unsigned short* WpH = P2H + 786432;                     // [128][512]  fp16  (128 KB)

    proj_kernel<<<dim3(DIM/64, (DEP*BSZ)/64, 2), 256, 0, stream>>>(
        outs, graph, Wt, bt, Wp, P1, P2H, WpH);
    fused_kernel<<<(DEP/2)*BSZ, 256, 0, stream>>>(P1, P2H, WpH, bp, out);
}